// Round 7
// baseline (346.257 us; speedup 1.0000x reference)
//
#include <hip/hip_runtime.h>
#include <hip/hip_cooperative_groups.h>
#include <math.h>

namespace cg = cooperative_groups;

// Problem constants (fixed by reference)
#define BATCH 2
#define SEQ   1024
#define DM    1024   // D_MODEL
#define MMEM  128    // memory slots
#define MEMD  512    // MEM_DIM
#define RELH  512    // REL_HID
#define KVLD  2560   // ld of combined [keys|values|m_part]
#define QLD   1536   // ld of combined [queries|q_part]
#define NBLK  512    // cooperative grid size (2 blocks/CU)

typedef _Float16 f16;
typedef __attribute__((ext_vector_type(2))) _Float16 f16x2;
typedef __attribute__((ext_vector_type(4))) _Float16 f16x4;
typedef __attribute__((ext_vector_type(8))) _Float16 f16x8;
typedef __attribute__((ext_vector_type(4))) float    f32x4;

__device__ inline float dot2acc(f16x2 a, f16x2 b, float c) {
#if __has_builtin(__builtin_amdgcn_fdot2)
    return __builtin_amdgcn_fdot2(a, b, c, false);
#else
    return c + (float)a[0] * (float)b[0] + (float)a[1] * (float)b[1];
#endif
}
__device__ inline f16x2 relu2(f16x2 a) {
    f16x2 z = { (_Float16)0.0f, (_Float16)0.0f };
#if __has_builtin(__builtin_elementwise_max)
    return __builtin_elementwise_max(a, z);
#else
    f16x2 r;
    r[0] = a[0] > z[0] ? a[0] : z[0];
    r[1] = a[1] > z[1] ? a[1] : z[1];
    return r;
#endif
}

// async global->LDS, 16B per lane (wave-uniform LDS base + lane*16)
__device__ inline void llds16(const void* gp, void* lp) {
    __builtin_amdgcn_global_load_lds(
        (const __attribute__((address_space(1))) void*)gp,
        (__attribute__((address_space(3))) void*)lp,
        16, 0, 0);
}

__device__ inline void cast8(const float* __restrict__ in, f16* __restrict__ out, int i) {
    const float4* p = (const float4*)in + (size_t)i * 2;
    float4 a = p[0], b = p[1];
    f16x8 v = { (f16)a.x, (f16)a.y, (f16)a.z, (f16)a.w,
                (f16)b.x, (f16)b.y, (f16)b.z, (f16)b.w };
    *(f16x8*)(out + (size_t)i * 8) = v;
}

// transpose-cast one 64x64 tile; smem-backed. Leading sync protects prior use.
__device__ inline void tr_tile(char* smem, const float* __restrict__ in,
                               f16* __restrict__ out, int R, int C, int tile) {
    float (*t)[65] = (float(*)[65])smem;
    const int tid = threadIdx.x;
    const int ctiles = C >> 6;
    const int r0 = (tile / ctiles) * 64, c0 = (tile % ctiles) * 64;
    __syncthreads();
    #pragma unroll
    for (int i = 0; i < 16; ++i) {
        int idx = tid + 256 * i;
        int r = idx >> 6, c = idx & 63;
        t[c][r] = in[(size_t)(r0 + r) * C + c0 + c];
    }
    __syncthreads();
    #pragma unroll
    for (int i = 0; i < 16; ++i) {
        int idx = tid + 256 * i;
        int ro = idx >> 6, co = idx & 63;
        out[(size_t)(c0 + ro) * R + r0 + co] = (f16)t[ro][co];
    }
}

// ---------------------------------------------------------------------------
// MFMA GEMM core: C(f32,opt)/C2(f16,opt) = A @ Bt^T + bias.
// BM=64, BN template (64/128), BK=64, 256 thr = 4 waves.
// global_load_lds staging (inverse-swizzled source, linear LDS, XOR frag read),
// double-buffered.
// ---------------------------------------------------------------------------
template<int BN>
__device__ __forceinline__ void gemm_core(
    const f16* __restrict__ A, const f16* __restrict__ Bt,
    const float* __restrict__ bias, float* __restrict__ C,
    f16* __restrict__ C2, int N, int K, int ldc,
    int bx, int by, f16* Al, f16* Bl)
{
    constexpr int NBW = BN / 32;   // B staging llds16 per wave
    constexpr int NF  = BN / 64;   // n-fragments per wave
    const int tid = threadIdx.x, lane = tid & 63, wid = tid >> 6;
    const size_t row0 = (size_t)by * 64;
    const size_t col0 = (size_t)bx * BN;
    const int lrow = lane >> 3;
    const int lcs  = (lane & 7) ^ lrow;
    const int r15 = lane & 15, l4 = lane >> 4;

    f32x4 acc[4][NF];
    #pragma unroll
    for (int m = 0; m < 4; ++m)
        #pragma unroll
        for (int n = 0; n < NF; ++n) acc[m][n] = (f32x4){0.f, 0.f, 0.f, 0.f};

    auto STAGE = [&](int buf, int kt) {
        const f16* Ab = A + row0 * K + (size_t)kt * 64;
        const f16* Bb = Bt + col0 * K + (size_t)kt * 64;
        #pragma unroll
        for (int j = 0; j < 2; ++j) {
            const int c = wid * 2 + j;
            llds16(Ab + (size_t)(c * 8 + lrow) * K + lcs * 8,
                   Al + buf * 4096 + c * 512);
        }
        #pragma unroll
        for (int j = 0; j < NBW; ++j) {
            const int c = wid * NBW + j;
            llds16(Bb + (size_t)(c * 8 + lrow) * K + lcs * 8,
                   Bl + buf * (BN * 64) + c * 512);
        }
    };

    STAGE(0, 0);
    __syncthreads();

    const int nk = K >> 6;
    int cur = 0;
    for (int kt = 0; kt < nk; ++kt) {
        if (kt + 1 < nk) STAGE(cur ^ 1, kt + 1);
        #pragma unroll
        for (int kk = 0; kk < 2; ++kk) {
            f16x8 af[4], bfr[NF];
            #pragma unroll
            for (int m = 0; m < 4; ++m) {
                const int rowA = m * 16 + r15;
                af[m] = *(const f16x8*)(
                    Al + cur * 4096 + rowA * 64 + (((kk * 4 + l4) ^ (r15 & 7)) * 8));
            }
            #pragma unroll
            for (int n = 0; n < NF; ++n) {
                const int rowB = wid * (BN / 4) + n * 16 + r15;
                bfr[n] = *(const f16x8*)(
                    Bl + cur * (BN * 64) + rowB * 64 + (((kk * 4 + l4) ^ (r15 & 7)) * 8));
            }
            #pragma unroll
            for (int m = 0; m < 4; ++m)
                #pragma unroll
                for (int n = 0; n < NF; ++n)
                    acc[m][n] = __builtin_amdgcn_mfma_f32_16x16x32_f16(
                        af[m], bfr[n], acc[m][n], 0, 0, 0);
        }
        __syncthreads();
        cur ^= 1;
    }

    // C/D layout: col = lane&15, row = (lane>>4)*4 + j
    const int cr = l4, cc = r15;
    #pragma unroll
    for (int n = 0; n < NF; ++n) {
        const size_t col = col0 + wid * (BN / 4) + n * 16 + cc;
        const float bvv = bias ? bias[col] : 0.f;
        #pragma unroll
        for (int m = 0; m < 4; ++m) {
            #pragma unroll
            for (int j = 0; j < 4; ++j) {
                const size_t row = row0 + m * 16 + cr * 4 + j;
                const float v = acc[m][n][j] + bvv;
                if (C)  C[row * ldc + col] = v;
                if (C2) C2[row * ldc + col] = (f16)v;
            }
        }
    }
}

// ---------------------------------------------------------------------------
// fused relevance + scores + softmax + PV for one 8-s-row tile.
// smem carve: u [0,41984) | rel_s [41984,46080) | Ps [46080,48256)
// ---------------------------------------------------------------------------
__device__ void relattn_body(char* smem, int blk,
    const f16* __restrict__ qcat, const f16* __restrict__ kvm,
    const f16* __restrict__ Vt, const f16* __restrict__ mpt,
    const float* __restrict__ W2, const float* __restrict__ b2,
    f16* __restrict__ attn_out, float* __restrict__ attn_w)
{
    char* u = smem;
    float* rel_s = (float*)(smem + 41984);
    f16* Ps = (f16*)(smem + 46080);

    const int tid = threadIdx.x;
    const int b = blk >> 7, st = blk & 127;
    const size_t rowbase = (size_t)b * SEQ + st * 8;
    const int w = tid >> 6, lane = tid & 63;
    const int l15 = lane & 15, l4 = lane >> 4;

    // ---------------- Phase R: relevance -> rel_s ----------------
    {
        f16* qs  = (f16*)u;                 // [8][512]  8 KB
        f16* mps = (f16*)(u + 8192);        // [64][256] 32 KB
        f16* w2s = (f16*)(u + 40960);       // [512]     1 KB

        {
            int r = tid >> 5, c = tid & 31;
            const f16* src = qcat + (rowbase + r) * QLD + 1024 + c * 16;
            *(f16x8*)(qs + r * 512 + c * 16)     = *(const f16x8*)(src);
            *(f16x8*)(qs + r * 512 + c * 16 + 8) = *(const f16x8*)(src + 8);
        }
        if (tid < 128) {
            float4 w4 = *(const float4*)(W2 + tid * 4);
            f16x4 hv = { (f16)w4.x, (f16)w4.y, (f16)w4.z, (f16)w4.w };
            *(f16x4*)(w2s + tid * 4) = hv;
        }
        const float b2v = b2[0];
        const int sg = w;

        float acc00 = 0.f, acc01 = 0.f, acc10 = 0.f, acc11 = 0.f;
        const f16* mptb = mpt + (size_t)b * 65536;

        for (int hc = 0; hc < 4; ++hc) {
            __syncthreads();
            {
                const f16x8* src = (const f16x8*)(mptb + hc * 16384);
                f16x8* dst = (f16x8*)mps;
                #pragma unroll
                for (int k = 0; k < 8; ++k) dst[tid + 256 * k] = src[tid + 256 * k];
            }
            __syncthreads();

            #pragma unroll 4
            for (int step = 0; step < 16; ++step) {
                const int habs = hc * 128 + step * 8;
                uint4 q0u = *(const uint4*)(qs + (2 * sg) * 512 + habs);
                uint4 q1u = *(const uint4*)(qs + (2 * sg + 1) * 512 + habs);
                uint4 wu  = *(const uint4*)(w2s + habs);
                const unsigned* q0p = (const unsigned*)&q0u;
                const unsigned* q1p = (const unsigned*)&q1u;
                const unsigned* wp_ = (const unsigned*)&wu;
                #pragma unroll
                for (int jj = 0; jj < 4; ++jj) {
                    uint2 mpu = *(const uint2*)(mps + ((step * 4 + jj) * 128 + 2 * lane) * 2);
                    f16x2 m0 = __builtin_bit_cast(f16x2, mpu.x);
                    f16x2 m1 = __builtin_bit_cast(f16x2, mpu.y);
                    f16x2 wp = __builtin_bit_cast(f16x2, wp_[jj]);
                    f16x2 q0 = __builtin_bit_cast(f16x2, q0p[jj]);
                    f16x2 q1 = __builtin_bit_cast(f16x2, q1p[jj]);
                    acc00 = dot2acc(relu2(q0 + m0), wp, acc00);
                    acc01 = dot2acc(relu2(q0 + m1), wp, acc01);
                    acc10 = dot2acc(relu2(q1 + m0), wp, acc10);
                    acc11 = dot2acc(relu2(q1 + m1), wp, acc11);
                }
            }
        }

        rel_s[(2 * sg) * 128 + 2 * lane]         = 1.f / (1.f + __expf(-(acc00 + b2v)));
        rel_s[(2 * sg) * 128 + 2 * lane + 1]     = 1.f / (1.f + __expf(-(acc01 + b2v)));
        rel_s[(2 * sg + 1) * 128 + 2 * lane]     = 1.f / (1.f + __expf(-(acc10 + b2v)));
        rel_s[(2 * sg + 1) * 128 + 2 * lane + 1] = 1.f / (1.f + __expf(-(acc11 + b2v)));
    }
    __syncthreads();   // rel_s ready; qs/mps dead -> sc may overwrite

    float* sc = (float*)u;   // [4][16][128] 32 KB

    // ---------------- Phase S: QK^T partials over k-quarter ----------------
    {
        f32x4 aq[8];
        #pragma unroll
        for (int n = 0; n < 8; ++n) aq[n] = (f32x4){0.f, 0.f, 0.f, 0.f};
        #pragma unroll
        for (int k4 = 0; k4 < 8; ++k4) {
            const int k0 = w * 256 + k4 * 32 + l4 * 8;
            f16x8 af = *(const f16x8*)(qcat + (rowbase + (l15 & 7)) * QLD + k0);
            #pragma unroll
            for (int n = 0; n < 8; ++n) {
                f16x8 bf = *(const f16x8*)(kvm + (size_t)(b * 128 + n * 16 + l15) * KVLD + k0);
                aq[n] = __builtin_amdgcn_mfma_f32_16x16x32_f16(af, bf, aq[n], 0, 0, 0);
            }
        }
        #pragma unroll
        for (int n = 0; n < 8; ++n)
            #pragma unroll
            for (int j = 0; j < 4; ++j)
                sc[(w * 16 + l4 * 4 + j) * 128 + n * 16 + l15] = aq[n][j];
    }
    __syncthreads();

    // ---------------- reduce partials, *rel/32, softmax ----------------
    {
        const int r = tid >> 5, seg = tid & 31;
        float4 xs = {0.f, 0.f, 0.f, 0.f};
        #pragma unroll
        for (int ww = 0; ww < 4; ++ww) {
            float4 p = *(const float4*)(sc + (ww * 16 + r) * 128 + seg * 4);
            xs.x += p.x; xs.y += p.y; xs.z += p.z; xs.w += p.w;
        }
        float4 rl = *(const float4*)(rel_s + r * 128 + seg * 4);
        float x[4];
        x[0] = xs.x * 0.03125f * rl.x; x[1] = xs.y * 0.03125f * rl.y;
        x[2] = xs.z * 0.03125f * rl.z; x[3] = xs.w * 0.03125f * rl.w;
        float mx = fmaxf(fmaxf(x[0], x[1]), fmaxf(x[2], x[3]));
        #pragma unroll
        for (int d = 1; d < 32; d <<= 1) mx = fmaxf(mx, __shfl_xor(mx, d));
        float ss = 0.f;
        #pragma unroll
        for (int c = 0; c < 4; ++c) { x[c] = __expf(x[c] - mx); ss += x[c]; }
        #pragma unroll
        for (int d = 1; d < 32; d <<= 1) ss += __shfl_xor(ss, d);
        const float inv = 1.f / ss;
        #pragma unroll
        for (int c = 0; c < 4; ++c) x[c] *= inv;
        float4 o = { x[0], x[1], x[2], x[3] };
        *(float4*)(attn_w + (rowbase + r) * 128 + seg * 4) = o;
        f16x4 ph = { (f16)x[0], (f16)x[1], (f16)x[2], (f16)x[3] };
        *(f16x4*)(Ps + r * 136 + seg * 4) = ph;
    }
    __syncthreads();

    // ---------------- Phase P: PV over d-quarter ----------------
    {
        f16x8 pa[4];
        #pragma unroll
        for (int k = 0; k < 4; ++k)
            pa[k] = *(const f16x8*)(Ps + (l15 & 7) * 136 + k * 32 + l4 * 8);
        #pragma unroll
        for (int n2 = 0; n2 < 16; ++n2) {
            f32x4 ac = (f32x4){0.f, 0.f, 0.f, 0.f};
            const int d0 = w * 256 + n2 * 16;
            #pragma unroll
            for (int k = 0; k < 4; ++k) {
                f16x8 bf = *(const f16x8*)(Vt + (size_t)(d0 + l15) * 256 + b * 128 + k * 32 + l4 * 8);
                ac = __builtin_amdgcn_mfma_f32_16x16x32_f16(pa[k], bf, ac, 0, 0, 0);
            }
            if (l4 < 2) {
                #pragma unroll
                for (int j = 0; j < 4; ++j)
                    attn_out[(rowbase + l4 * 4 + j) * 1024 + d0 + l15] = (f16)ac[j];
            }
        }
    }
}

// ---------------------------------------------------------------------------
struct MegaArgs {
    const float *hs, *mem, *Wq, *bq, *Wk, *bk, *Wv, *bv, *Wo, *bo, *W1, *b1, *W2, *b2;
    float *out, *attnw;
    f16 *hsA, *mem_f16, *Wq_f16, *btbig, *btcomb, *Wo_t, *W1q_t, *qcat, *kvm, *Vt, *mpt;
    float *bcomb, *bqcomb;
};

// ---------------------------------------------------------------------------
// One cooperative kernel; 5 phases separated by grid.sync().
// 512 blocks x 256 thr; 48 KB LDS (3 blk/CU), VGPR capped for 2 blk/CU.
// ---------------------------------------------------------------------------
__global__ __launch_bounds__(256, 2) void mega(MegaArgs a)
{
    cg::grid_group grid = cg::this_grid();
    __shared__ __align__(16) char smem[49152];
    const int bid = blockIdx.x;
    const int tid = threadIdx.x;

    f16* attn_out = a.hsA;   // hs_f16 consumed by P3, buffer reused by P4

    // ---- P1: casts + transposes + bias vectors (2561 units) ----
    for (int u = bid; u < 2561; u += NBLK) {
        if (u < 1024) {
            cast8(a.hs, a.hsA, u * 256 + tid);
        } else if (u < 1088) {
            cast8(a.mem, a.mem_f16, (u - 1024) * 256 + tid);
        } else if (u < 1600) {
            cast8(a.Wq, a.Wq_f16, (u - 1088) * 256 + tid);
        } else if (u < 1856) {
            tr_tile(smem, a.Wq, a.btbig, 1024, 1024, u - 1600);
        } else if (u < 1984) {
            tr_tile(smem, a.Wk, a.btcomb, 512, 1024, u - 1856);
        } else if (u < 2112) {
            tr_tile(smem, a.Wv, a.btcomb + (size_t)1024 * 512, 512, 1024, u - 1984);
        } else if (u < 2368) {
            tr_tile(smem, a.Wo, a.Wo_t, 1024, 1024, u - 2112);
        } else if (u < 2496) {
            tr_tile(smem, a.W1, a.W1q_t, 1024, 512, u - 2368);
        } else if (u < 2560) {
            tr_tile(smem, a.W1 + (size_t)1024 * 512, a.btcomb + (size_t)2048 * 512,
                    512, 512, u - 2496);
        } else {
            #pragma unroll
            for (int j = 0; j < 10; ++j) {
                int g = tid + 256 * j;
                float v = (g < 1024) ? a.bk[g] : (g < 2048) ? a.bv[g - 1024]
                                               : a.b1[g - 2048];
                a.bcomb[g] = v;
            }
            #pragma unroll
            for (int j = 0; j < 4; ++j) {
                int g = tid + 256 * j;
                a.bqcomb[g] = a.bq[g];
            }
        }
    }
    grid.sync();

    // ---- P2: kvm GEMM + Wq1 weight-combine + bias-combine ----
    if (bid < 80) {
        gemm_core<128>(a.mem_f16, a.btcomb, a.bcomb, nullptr, a.kvm,
                       KVLD, MEMD, KVLD, bid % 20, bid / 20,
                       (f16*)smem, (f16*)(smem + 16384));
    } else if (bid < 144) {
        const int i = bid - 80;
        gemm_core<128>(a.W1q_t, a.Wq_f16, nullptr, nullptr,
                       a.btbig + (size_t)1024 * DM,
                       DM, DM, DM, i % 8, i / 8,
                       (f16*)smem, (f16*)(smem + 16384));
    } else if (bid == 144) {
        float* bqs = (float*)smem;
        __syncthreads();
        #pragma unroll
        for (int j = 0; j < 4; ++j) bqs[tid + 256 * j] = a.bq[tid + 256 * j];
        __syncthreads();
        #pragma unroll
        for (int rr = 0; rr < 2; ++rr) {
            const int j = tid + rr * 256;
            float acc = 0.f;
            for (int k8 = 0; k8 < 128; ++k8) {
                f16x8 wv = *(const f16x8*)(a.W1q_t + (size_t)j * 1024 + k8 * 8);
                #pragma unroll
                for (int e = 0; e < 8; ++e) acc += bqs[k8 * 8 + e] * (float)wv[e];
            }
            a.bqcomb[1024 + j] = acc;
        }
    }
    grid.sync();

    // ---- P3: qcat GEMM (384 tiles) + posttrans (Vt 64, mpt 8) ----
    if (bid < 384) {
        gemm_core<128>(a.hsA, a.btbig, a.bqcomb, nullptr, a.qcat,
                       QLD, DM, QLD, bid % 12, bid / 12,
                       (f16*)smem, (f16*)(smem + 16384));
    } else if (bid < 448) {
        // transpose values [256][KVLD cols 1024..2048) -> Vt [1024][256]
        f16 (*tf)[72] = (f16(*)[72])smem;
        const f16* vals = a.kvm + 1024;
        const int pb = bid - 384;
        const int r0 = (pb / 16) * 64, c0 = (pb % 16) * 64;
        #pragma unroll
        for (int kq = 0; kq < 2; ++kq) {
            int idx = tid + 256 * kq;
            int r = idx >> 3, ch = idx & 7;
            *(f16x8*)(&tf[r][ch * 8]) =
                *(const f16x8*)(vals + (size_t)(r0 + r) * KVLD + c0 + ch * 8);
        }
        __syncthreads();
        #pragma unroll
        for (int kq = 0; kq < 2; ++kq) {
            int idx = tid + 256 * kq;
            int oc = idx & 63, og = idx >> 6;
            f16x8 v;
            #pragma unroll
            for (int j = 0; j < 8; ++j) v[j] = tf[og * 8 + j][oc];
            *(f16x8*)(a.Vt + (size_t)(c0 + oc) * 256 + r0 + og * 8) = v;
        }
    } else if (bid < 456) {
        // mpt: m_part rows (kvm cols 2048..2560) -> [b][256 h2][128 m][2]
        f16 (*t2)[136] = (f16(*)[136])smem;
        const f16* mpart = a.kvm + 2048;
        const int mb = bid - 448, b = mb >> 2, hc = mb & 3;
        #pragma unroll
        for (int k = 0; k < 8; ++k) {
            int idx = tid + 256 * k;
            int m = idx >> 4, hq = idx & 15;
            *(f16x8*)(&t2[m][hq * 8]) =
                *(const f16x8*)(mpart + (size_t)(b * 128 + m) * KVLD + hc * 128 + hq * 8);
        }
        __syncthreads();
        #pragma unroll
        for (int k = 0; k < 32; ++k) {
            int idx = tid + 256 * k;
            int h2l = idx >> 7, m = idx & 127;
            f16x2 v = { t2[m][h2l * 2], t2[m][h2l * 2 + 1] };
            *(f16x2*)(a.mpt + ((size_t)b * 256 + hc * 64 + h2l) * 256 + m * 2) = v;
        }
    }
    grid.sync();

    // ---- P4: fused relevance + attention (256 tiles) ----
    if (bid < 256) {
        relattn_body(smem, bid, a.qcat, a.kvm, a.Vt, a.mpt,
                     a.W2, a.b2, attn_out, a.attnw);
    }
    grid.sync();

    // ---- P5: out = attn_out @ Wo + bo (512 tiles, BN=64) ----
    gemm_core<64>(attn_out, a.Wo_t, a.bo, a.out, nullptr, DM, DM, DM,
                  bid % 16, bid / 16, (f16*)smem, (f16*)(smem + 16384));
}

// ---------------------------------------------------------------------------
extern "C" void kernel_launch(void* const* d_in, const int* in_sizes, int n_in,
                              void* d_out, int out_size, void* d_ws, size_t ws_size,
                              hipStream_t stream)
{
    MegaArgs a;
    a.hs  = (const float*)d_in[0];
    a.mem = (const float*)d_in[1];
    a.Wq  = (const float*)d_in[2];
    a.bq  = (const float*)d_in[3];
    a.Wk  = (const float*)d_in[4];
    a.bk  = (const float*)d_in[5];
    a.Wv  = (const float*)d_in[6];
    a.bv  = (const float*)d_in[7];
    a.Wo  = (const float*)d_in[8];
    a.bo  = (const float*)d_in[9];
    a.W1  = (const float*)d_in[10];
    a.b1  = (const float*)d_in[11];
    a.W2  = (const float*)d_in[12];
    a.b2  = (const float*)d_in[13];

    a.out   = (float*)d_out;
    a.attnw = a.out + (size_t)BATCH * SEQ * DM;

    char* wp = (char*)d_ws;
    a.hsA     = (f16*)wp;  wp += (size_t)BATCH * SEQ * DM * 2;     // hs_f16 -> attn_out
    a.mem_f16 = (f16*)wp;  wp += (size_t)BATCH * MMEM * MEMD * 2;
    a.Wq_f16  = (f16*)wp;  wp += (size_t)DM * DM * 2;
    a.btbig   = (f16*)wp;  wp += (size_t)QLD * DM * 2;
    a.btcomb  = (f16*)wp;  wp += (size_t)KVLD * MEMD * 2;
    a.Wo_t    = (f16*)wp;  wp += (size_t)DM * DM * 2;
    a.W1q_t   = (f16*)wp;  wp += (size_t)RELH * DM * 2;
    a.qcat    = (f16*)wp;  wp += (size_t)BATCH * SEQ * QLD * 2;
    a.kvm     = (f16*)wp;  wp += (size_t)BATCH * MMEM * KVLD * 2;
    a.Vt      = (f16*)wp;  wp += (size_t)DM * BATCH * MMEM * 2;
    a.mpt     = (f16*)wp;  wp += (size_t)BATCH * MMEM * RELH * 2;
    a.bcomb   = (float*)wp; wp += (size_t)KVLD * 4;
    a.bqcomb  = (float*)wp; wp += (size_t)QLD * 4;

    void* kp[] = { (void*)&a };
    hipLaunchCooperativeKernel((const void*)mega, dim3(NBLK), dim3(256),
                               kp, 0, stream);
}

// Round 8
// 92.779 us; speedup vs baseline: 3.7321x; 3.7321x over previous
//
#include <hip/hip_runtime.h>
#include <math.h>

// Problem constants (fixed by reference)
#define BATCH 2
#define SEQ   1024
#define DM    1024   // D_MODEL
#define MMEM  128    // memory slots
#define MEMD  512    // MEM_DIM
#define RELH  512    // REL_HID
#define KVLD  2560   // ld of combined [keys|values|m_part]
#define QLD   1536   // ld of combined [queries|q_part]

typedef _Float16 f16;
typedef __attribute__((ext_vector_type(2))) _Float16 f16x2;
typedef __attribute__((ext_vector_type(4))) _Float16 f16x4;
typedef __attribute__((ext_vector_type(8))) _Float16 f16x8;
typedef __attribute__((ext_vector_type(4))) float    f32x4;

__device__ inline float dot2acc(f16x2 a, f16x2 b, float c) {
#if __has_builtin(__builtin_amdgcn_fdot2)
    return __builtin_amdgcn_fdot2(a, b, c, false);
#else
    return c + (float)a[0] * (float)b[0] + (float)a[1] * (float)b[1];
#endif
}
__device__ inline f16x2 relu2(f16x2 a) {
    f16x2 z = { (_Float16)0.0f, (_Float16)0.0f };
#if __has_builtin(__builtin_elementwise_max)
    return __builtin_elementwise_max(a, z);
#else
    f16x2 r;
    r[0] = a[0] > z[0] ? a[0] : z[0];
    r[1] = a[1] > z[1] ? a[1] : z[1];
    return r;
#endif
}

// async global->LDS, 16B per lane (wave-uniform LDS base + lane*16)
__device__ inline void llds16(const void* gp, void* lp) {
    __builtin_amdgcn_global_load_lds(
        (const __attribute__((address_space(1))) void*)gp,
        (__attribute__((address_space(3))) void*)lp,
        16, 0, 0);
}

__device__ inline void cast8(const float* __restrict__ in, f16* __restrict__ out, int i) {
    const float4* p = (const float4*)in + (size_t)i * 2;
    float4 a = p[0], b = p[1];
    f16x8 v = { (f16)a.x, (f16)a.y, (f16)a.z, (f16)a.w,
                (f16)b.x, (f16)b.y, (f16)b.z, (f16)b.w };
    *(f16x8*)(out + (size_t)i * 8) = v;
}

__device__ inline void tr_tile(float (*t)[65], const float* __restrict__ in,
                               f16* __restrict__ out, int R, int C, int tile) {
    const int tid = threadIdx.x;
    const int ctiles = C >> 6;
    const int r0 = (tile / ctiles) * 64, c0 = (tile % ctiles) * 64;
    #pragma unroll
    for (int i = 0; i < 16; ++i) {
        int idx = tid + 256 * i;
        int r = idx >> 6, c = idx & 63;
        t[c][r] = in[(size_t)(r0 + r) * C + c0 + c];
    }
    __syncthreads();
    #pragma unroll
    for (int i = 0; i < 16; ++i) {
        int idx = tid + 256 * i;
        int ro = idx >> 6, co = idx & 63;
        out[(size_t)(c0 + ro) * R + r0 + co] = (f16)t[ro][co];
    }
}

// ---------------------------------------------------------------------------
// L1 prep: all casts + transposes + bias vectors. grid 2561 x 256.
// ---------------------------------------------------------------------------
__global__ __launch_bounds__(256) void prep(
    const float* __restrict__ hs, const float* __restrict__ mem,
    const float* __restrict__ Wq, const float* __restrict__ Wk,
    const float* __restrict__ Wv, const float* __restrict__ Wo,
    const float* __restrict__ W1,
    const float* __restrict__ bq, const float* __restrict__ bk,
    const float* __restrict__ bv, const float* __restrict__ b1,
    f16* __restrict__ hs_f16, f16* __restrict__ mem_f16,
    f16* __restrict__ Wq_f16, f16* __restrict__ btbig,
    f16* __restrict__ btcomb, f16* __restrict__ Wo_t,
    f16* __restrict__ W1q_t, float* __restrict__ bcomb,
    float* __restrict__ bqcomb)
{
    __shared__ float t[64][65];
    const int bid = blockIdx.x, tid = threadIdx.x;

    if (bid < 1024) {                         // hs f32->f16
        cast8(hs, hs_f16, bid * 256 + tid);
    } else if (bid < 1088) {                  // mem f32->f16
        cast8(mem, mem_f16, (bid - 1024) * 256 + tid);
    } else if (bid < 1600) {                  // Wq straight cast (for Wq1 Bt)
        cast8(Wq, Wq_f16, (bid - 1088) * 256 + tid);
    } else if (bid < 1856) {                  // Wq^T -> btbig rows [0,1024)
        tr_tile(t, Wq, btbig, 1024, 1024, bid - 1600);
    } else if (bid < 1984) {                  // Wk^T -> btcomb rows [0,1024)
        tr_tile(t, Wk, btcomb, 512, 1024, bid - 1856);
    } else if (bid < 2112) {                  // Wv^T -> btcomb rows [1024,2048)
        tr_tile(t, Wv, btcomb + (size_t)1024 * 512, 512, 1024, bid - 1984);
    } else if (bid < 2368) {                  // Wo^T
        tr_tile(t, Wo, Wo_t, 1024, 1024, bid - 2112);
    } else if (bid < 2496) {                  // W1q^T
        tr_tile(t, W1, W1q_t, 1024, 512, bid - 2368);
    } else if (bid < 2560) {                  // W1m^T -> btcomb rows [2048,2560)
        tr_tile(t, W1 + (size_t)1024 * 512, btcomb + (size_t)2048 * 512,
                512, 512, bid - 2496);
    } else {                                  // bias vectors
        #pragma unroll
        for (int j = 0; j < 10; ++j) {
            int g = tid + 256 * j;
            float v = (g < 1024) ? bk[g] : (g < 2048) ? bv[g - 1024] : b1[g - 2048];
            bcomb[g] = v;
        }
        #pragma unroll
        for (int j = 0; j < 4; ++j) {
            int g = tid + 256 * j;
            bqcomb[g] = bq[g];                // cols [0,1024) of qcat bias
        }
    }
}

// ---------------------------------------------------------------------------
// MFMA GEMM core: C(f32,opt)/C2(f16,opt) = A @ Bt^T + bias.
// BM=64, BN template (64/128), BK=64, 256 thr = 4 waves.
// A row stride lda, Bt row stride ldb (both >= K).
// global_load_lds staging (inverse-swizzled source, linear LDS, XOR frag read),
// double-buffered.
// ---------------------------------------------------------------------------
template<int BN>
__device__ __forceinline__ void gemm_core(
    const f16* __restrict__ A, const f16* __restrict__ Bt,
    const float* __restrict__ bias, float* __restrict__ C,
    f16* __restrict__ C2, int N, int K, int ldc, int lda, int ldb,
    int bx, int by, f16* Al, f16* Bl)
{
    constexpr int NBW = BN / 32;   // B staging llds16 per wave
    constexpr int NF  = BN / 64;   // n-fragments per wave
    const int tid = threadIdx.x, lane = tid & 63, wid = tid >> 6;
    const size_t row0 = (size_t)by * 64;
    const size_t col0 = (size_t)bx * BN;
    const int lrow = lane >> 3;
    const int lcs  = (lane & 7) ^ lrow;
    const int r15 = lane & 15, l4 = lane >> 4;

    f32x4 acc[4][NF];
    #pragma unroll
    for (int m = 0; m < 4; ++m)
        #pragma unroll
        for (int n = 0; n < NF; ++n) acc[m][n] = (f32x4){0.f, 0.f, 0.f, 0.f};

    auto STAGE = [&](int buf, int kt) {
        const f16* Ab = A + row0 * lda + (size_t)kt * 64;
        const f16* Bb = Bt + col0 * ldb + (size_t)kt * 64;
        #pragma unroll
        for (int j = 0; j < 2; ++j) {
            const int c = wid * 2 + j;
            llds16(Ab + (size_t)(c * 8 + lrow) * lda + lcs * 8,
                   Al + buf * 4096 + c * 512);
        }
        #pragma unroll
        for (int j = 0; j < NBW; ++j) {
            const int c = wid * NBW + j;
            llds16(Bb + (size_t)(c * 8 + lrow) * ldb + lcs * 8,
                   Bl + buf * (BN * 64) + c * 512);
        }
    };

    STAGE(0, 0);
    __syncthreads();

    const int nk = K >> 6;
    int cur = 0;
    for (int kt = 0; kt < nk; ++kt) {
        if (kt + 1 < nk) STAGE(cur ^ 1, kt + 1);
        #pragma unroll
        for (int kk = 0; kk < 2; ++kk) {
            f16x8 af[4], bfr[NF];
            #pragma unroll
            for (int m = 0; m < 4; ++m) {
                const int rowA = m * 16 + r15;
                af[m] = *(const f16x8*)(
                    Al + cur * 4096 + rowA * 64 + (((kk * 4 + l4) ^ (r15 & 7)) * 8));
            }
            #pragma unroll
            for (int n = 0; n < NF; ++n) {
                const int rowB = wid * (BN / 4) + n * 16 + r15;
                bfr[n] = *(const f16x8*)(
                    Bl + cur * (BN * 64) + rowB * 64 + (((kk * 4 + l4) ^ (r15 & 7)) * 8));
            }
            #pragma unroll
            for (int m = 0; m < 4; ++m)
                #pragma unroll
                for (int n = 0; n < NF; ++n)
                    acc[m][n] = __builtin_amdgcn_mfma_f32_16x16x32_f16(
                        af[m], bfr[n], acc[m][n], 0, 0, 0);
        }
        __syncthreads();
        cur ^= 1;
    }

    // C/D layout: col = lane&15, row = (lane>>4)*4 + j
    const int cr = l4, cc = r15;
    #pragma unroll
    for (int n = 0; n < NF; ++n) {
        const size_t col = col0 + wid * (BN / 4) + n * 16 + cc;
        const float bvv = bias ? bias[col] : 0.f;
        #pragma unroll
        for (int m = 0; m < 4; ++m) {
            #pragma unroll
            for (int j = 0; j < 4; ++j) {
                const size_t row = row0 + m * 16 + cr * 4 + j;
                const float v = acc[m][n][j] + bvv;
                if (C)  C[row * ldc + col] = v;
                if (C2) C2[row * ldc + col] = (f16)v;
            }
        }
    }
}

// ---------------------------------------------------------------------------
// L2: batched small GEMMs + bias-combine. grid 145 x 256.
//   [0,80)   kvm = mem @ [Wk|Wv|W1m] + [bk|bv|b1]   (N=2560, K=512)
//   [80,144) Wq1_t = W1q_t @ Wq_f16^T               (-> btbig rows [1024,1536))
//   144      bqcomb[1024..1536) = bq @ W1q
// ---------------------------------------------------------------------------
__global__ __launch_bounds__(256) void smallgemms(
    const f16* __restrict__ mem_f16, const f16* __restrict__ btcomb,
    const float* __restrict__ bcomb, f16* __restrict__ kvm,
    const f16* __restrict__ W1q_t, const f16* __restrict__ Wq_f16,
    f16* __restrict__ wq1t, const float* __restrict__ bq,
    float* __restrict__ bqcomb)
{
    __shared__ __align__(16) char smem[49152];
    f16* Al = (f16*)smem;
    f16* Bl = (f16*)(smem + 16384);
    const int bid = blockIdx.x;

    if (bid < 80) {
        gemm_core<128>(mem_f16, btcomb, bcomb, nullptr, kvm,
                       KVLD, MEMD, KVLD, MEMD, MEMD, bid % 20, bid / 20, Al, Bl);
    } else if (bid < 144) {
        const int i = bid - 80;
        gemm_core<128>(W1q_t, Wq_f16, nullptr, nullptr, wq1t,
                       DM, DM, DM, DM, DM, i % 8, i / 8, Al, Bl);
    } else {
        float* bqs = (float*)smem;
        const int tid = threadIdx.x;
        #pragma unroll
        for (int j = 0; j < 4; ++j) bqs[tid + 256 * j] = bq[tid + 256 * j];
        __syncthreads();
        #pragma unroll
        for (int rr = 0; rr < 2; ++rr) {
            const int j = tid + rr * 256;
            float acc = 0.f;
            for (int k8 = 0; k8 < 128; ++k8) {
                f16x8 wv = *(const f16x8*)(W1q_t + (size_t)j * 1024 + k8 * 8);
                #pragma unroll
                for (int e = 0; e < 8; ++e) acc += bqs[k8 * 8 + e] * (float)wv[e];
            }
            bqcomb[1024 + j] = acc;
        }
    }
}

// ---------------------------------------------------------------------------
// L3: qcat GEMM (384) + VoT GEMM (32) + mpt (8). grid 424 x 256.
//   VoT[1024][256] = Wo^T @ values^T  (values = kvm cols [1024,2048), +bv
//   already folded). out = P@Vo + bo later; (P@V)Wo == P(V@Wo) exactly.
// ---------------------------------------------------------------------------
__global__ __launch_bounds__(256) void biggemm(
    const f16* __restrict__ hs_f16, const f16* __restrict__ btbig,
    const float* __restrict__ bqcomb, f16* __restrict__ qcat,
    const f16* __restrict__ kvm, const f16* __restrict__ Wo_t,
    f16* __restrict__ VoT, f16* __restrict__ mpt)
{
    __shared__ __align__(16) char smem[49152];
    const int bid = blockIdx.x, tid = threadIdx.x;

    if (bid < 384) {
        gemm_core<128>(hs_f16, btbig, bqcomb, nullptr, qcat,
                       QLD, DM, QLD, DM, DM, bid % 12, bid / 12,
                       (f16*)smem, (f16*)(smem + 16384));
        return;
    }
    if (bid < 416) {
        // VoT = Wo_t @ values^T : A=Wo_t (M=1024, lda=DM), Bt=kvm+1024
        // (N=256 rows, ldb=KVLD), K=1024, C2=VoT ldc=256.
        const int i = bid - 384;
        gemm_core<128>(Wo_t, kvm + 1024, nullptr, nullptr, VoT,
                       256, DM, 256, DM, KVLD, i % 2, i / 2,
                       (f16*)smem, (f16*)(smem + 16384));
        return;
    }
    // mpt: m_part rows (kvm cols 2048..2560) -> [b][256 h2][128 m][2]
    f16 (*t2)[136] = (f16(*)[136])smem;
    const f16* mpart = kvm + 2048;
    const int mb = bid - 416, b = mb >> 2, hc = mb & 3;
    #pragma unroll
    for (int k = 0; k < 8; ++k) {
        int idx = tid + 256 * k;
        int m = idx >> 4, hq = idx & 15;
        *(f16x8*)(&t2[m][hq * 8]) =
            *(const f16x8*)(mpart + (size_t)(b * 128 + m) * KVLD + hc * 128 + hq * 8);
    }
    __syncthreads();
    #pragma unroll
    for (int k = 0; k < 32; ++k) {
        int idx = tid + 256 * k;
        int h2l = idx >> 7, m = idx & 127;
        f16x2 v = { t2[m][h2l * 2], t2[m][h2l * 2 + 1] };
        *(f16x2*)(mpt + ((size_t)b * 256 + hc * 64 + h2l) * 256 + m * 2) = v;
    }
}

// ---------------------------------------------------------------------------
// L4: fused relevance + scores + softmax + P@Vo + bo -> out (f32).
// grid 256 x 256 (8 s-rows/block).
// ---------------------------------------------------------------------------
__global__ __launch_bounds__(256) void relattn(
    const f16* __restrict__ qcat,    // [2048][QLD]: queries | q_part
    const f16* __restrict__ kvm,     // [256][KVLD]: keys in cols [0,1024)
    const f16* __restrict__ VoT,     // [1024][256]
    const f16* __restrict__ mpt,     // [b][256 h2][128 m][2]
    const float* __restrict__ W2,    // [512]
    const float* __restrict__ b2,    // [1]
    const float* __restrict__ bo,    // [1024]
    float* __restrict__ out,         // [2048][1024] f32
    float* __restrict__ attn_w)      // [2048][128]
{
    __shared__ __align__(16) char u[41984];      // qs|mps|w2s  then  sc
    __shared__ float rel_s[1024];                // [8][128] persistent
    __shared__ f16 Ps[8 * 136];

    const int tid = threadIdx.x;
    const int b = blockIdx.x >> 7, st = blockIdx.x & 127;
    const size_t rowbase = (size_t)b * SEQ + st * 8;
    const int w = tid >> 6, lane = tid & 63;
    const int l15 = lane & 15, l4 = lane >> 4;

    // ---------------- Phase R: relevance -> rel_s ----------------
    {
        f16* qs  = (f16*)u;                 // [8][512]  8 KB
        f16* mps = (f16*)(u + 8192);        // [64][256] 32 KB
        f16* w2s = (f16*)(u + 40960);       // [512]     1 KB

        {
            int r = tid >> 5, c = tid & 31;
            const f16* src = qcat + (rowbase + r) * QLD + 1024 + c * 16;
            *(f16x8*)(qs + r * 512 + c * 16)     = *(const f16x8*)(src);
            *(f16x8*)(qs + r * 512 + c * 16 + 8) = *(const f16x8*)(src + 8);
        }
        if (tid < 128) {
            float4 w4 = *(const float4*)(W2 + tid * 4);
            f16x4 hv = { (f16)w4.x, (f16)w4.y, (f16)w4.z, (f16)w4.w };
            *(f16x4*)(w2s + tid * 4) = hv;
        }
        const float b2v = b2[0];
        const int sg = w;

        float acc00 = 0.f, acc01 = 0.f, acc10 = 0.f, acc11 = 0.f;
        const f16* mptb = mpt + (size_t)b * 65536;

        for (int hc = 0; hc < 4; ++hc) {
            __syncthreads();
            {
                const f16x8* src = (const f16x8*)(mptb + hc * 16384);
                f16x8* dst = (f16x8*)mps;
                #pragma unroll
                for (int k = 0; k < 8; ++k) dst[tid + 256 * k] = src[tid + 256 * k];
            }
            __syncthreads();

            #pragma unroll 4
            for (int step = 0; step < 16; ++step) {
                const int habs = hc * 128 + step * 8;
                uint4 q0u = *(const uint4*)(qs + (2 * sg) * 512 + habs);
                uint4 q1u = *(const uint4*)(qs + (2 * sg + 1) * 512 + habs);
                uint4 wu  = *(const uint4*)(w2s + habs);
                const unsigned* q0p = (const unsigned*)&q0u;
                const unsigned* q1p = (const unsigned*)&q1u;
                const unsigned* wp_ = (const unsigned*)&wu;
                #pragma unroll
                for (int jj = 0; jj < 4; ++jj) {
                    uint2 mpu = *(const uint2*)(mps + ((step * 4 + jj) * 128 + 2 * lane) * 2);
                    f16x2 m0 = __builtin_bit_cast(f16x2, mpu.x);
                    f16x2 m1 = __builtin_bit_cast(f16x2, mpu.y);
                    f16x2 wp = __builtin_bit_cast(f16x2, wp_[jj]);
                    f16x2 q0 = __builtin_bit_cast(f16x2, q0p[jj]);
                    f16x2 q1 = __builtin_bit_cast(f16x2, q1p[jj]);
                    acc00 = dot2acc(relu2(q0 + m0), wp, acc00);
                    acc01 = dot2acc(relu2(q0 + m1), wp, acc01);
                    acc10 = dot2acc(relu2(q1 + m0), wp, acc10);
                    acc11 = dot2acc(relu2(q1 + m1), wp, acc11);
                }
            }
        }

        rel_s[(2 * sg) * 128 + 2 * lane]         = 1.f / (1.f + __expf(-(acc00 + b2v)));
        rel_s[(2 * sg) * 128 + 2 * lane + 1]     = 1.f / (1.f + __expf(-(acc01 + b2v)));
        rel_s[(2 * sg + 1) * 128 + 2 * lane]     = 1.f / (1.f + __expf(-(acc10 + b2v)));
        rel_s[(2 * sg + 1) * 128 + 2 * lane + 1] = 1.f / (1.f + __expf(-(acc11 + b2v)));
    }
    __syncthreads();   // rel_s ready; qs/mps dead -> sc may overwrite

    float* sc = (float*)u;   // [4][16][128] 32 KB

    // ---------------- Phase S: QK^T partials over k-quarter ----------------
    {
        f32x4 aq[8];
        #pragma unroll
        for (int n = 0; n < 8; ++n) aq[n] = (f32x4){0.f, 0.f, 0.f, 0.f};
        #pragma unroll
        for (int k4 = 0; k4 < 8; ++k4) {
            const int k0 = w * 256 + k4 * 32 + l4 * 8;
            f16x8 af = *(const f16x8*)(qcat + (rowbase + (l15 & 7)) * QLD + k0);
            #pragma unroll
            for (int n = 0; n < 8; ++n) {
                f16x8 bf = *(const f16x8*)(kvm + (size_t)(b * 128 + n * 16 + l15) * KVLD + k0);
                aq[n] = __builtin_amdgcn_mfma_f32_16x16x32_f16(af, bf, aq[n], 0, 0, 0);
            }
        }
        #pragma unroll
        for (int n = 0; n < 8; ++n)
            #pragma unroll
            for (int j = 0; j < 4; ++j)
                sc[(w * 16 + l4 * 4 + j) * 128 + n * 16 + l15] = aq[n][j];
    }
    __syncthreads();

    // ---------------- reduce partials, *rel/32, softmax ----------------
    {
        const int r = tid >> 5, seg = tid & 31;
        float4 xs = {0.f, 0.f, 0.f, 0.f};
        #pragma unroll
        for (int ww = 0; ww < 4; ++ww) {
            float4 p = *(const float4*)(sc + (ww * 16 + r) * 128 + seg * 4);
            xs.x += p.x; xs.y += p.y; xs.z += p.z; xs.w += p.w;
        }
        float4 rl = *(const float4*)(rel_s + r * 128 + seg * 4);
        float x[4];
        x[0] = xs.x * 0.03125f * rl.x; x[1] = xs.y * 0.03125f * rl.y;
        x[2] = xs.z * 0.03125f * rl.z; x[3] = xs.w * 0.03125f * rl.w;
        float mx = fmaxf(fmaxf(x[0], x[1]), fmaxf(x[2], x[3]));
        #pragma unroll
        for (int d = 1; d < 32; d <<= 1) mx = fmaxf(mx, __shfl_xor(mx, d));
        float ss = 0.f;
        #pragma unroll
        for (int c = 0; c < 4; ++c) { x[c] = __expf(x[c] - mx); ss += x[c]; }
        #pragma unroll
        for (int d = 1; d < 32; d <<= 1) ss += __shfl_xor(ss, d);
        const float inv = 1.f / ss;
        #pragma unroll
        for (int c = 0; c < 4; ++c) x[c] *= inv;
        float4 o = { x[0], x[1], x[2], x[3] };
        *(float4*)(attn_w + (rowbase + r) * 128 + seg * 4) = o;
        f16x4 ph = { (f16)x[0], (f16)x[1], (f16)x[2], (f16)x[3] };
        *(f16x4*)(Ps + r * 136 + seg * 4) = ph;
    }
    __syncthreads();

    // ---------------- Phase P: out = P @ Vo + bo over d-quarter ----------------
    {
        f16x8 pa[4];
        #pragma unroll
        for (int k = 0; k < 4; ++k)
            pa[k] = *(const f16x8*)(Ps + (l15 & 7) * 136 + k * 32 + l4 * 8);
        #pragma unroll
        for (int n2 = 0; n2 < 16; ++n2) {
            f32x4 ac = (f32x4){0.f, 0.f, 0.f, 0.f};
            const int d0 = w * 256 + n2 * 16;
            #pragma unroll
            for (int k = 0; k < 4; ++k) {
                f16x8 bf = *(const f16x8*)(VoT + (size_t)(d0 + l15) * 256 + b * 128 + k * 32 + l4 * 8);
                ac = __builtin_amdgcn_mfma_f32_16x16x32_f16(pa[k], bf, ac, 0, 0, 0);
            }
            if (l4 < 2) {
                const float bov = bo[d0 + l15];
                #pragma unroll
                for (int j = 0; j < 4; ++j)
                    out[(rowbase + l4 * 4 + j) * 1024 + d0 + l15] = ac[j] + bov;
            }
        }
    }
}

// ---------------------------------------------------------------------------
extern "C" void kernel_launch(void* const* d_in, const int* in_sizes, int n_in,
                              void* d_out, int out_size, void* d_ws, size_t ws_size,
                              hipStream_t stream)
{
    const float* hs  = (const float*)d_in[0];
    const float* mem = (const float*)d_in[1];
    const float* Wq  = (const float*)d_in[2];
    const float* bq  = (const float*)d_in[3];
    const float* Wk  = (const float*)d_in[4];
    const float* bk  = (const float*)d_in[5];
    const float* Wv  = (const float*)d_in[6];
    const float* bv  = (const float*)d_in[7];
    const float* Wo  = (const float*)d_in[8];
    const float* bo  = (const float*)d_in[9];
    const float* W1  = (const float*)d_in[10];  // (1536,512)
    const float* b1  = (const float*)d_in[11];
    const float* W2  = (const float*)d_in[12];
    const float* b2  = (const float*)d_in[13];

    float* out   = (float*)d_out;                       // (2,1024,1024)
    float* attnw = out + (size_t)BATCH * SEQ * DM;      // (2,1024,128)

    // workspace layout (16B-aligned, ~23 MB)
    char* wp = (char*)d_ws;
    f16* hs_f16  = (f16*)wp;  wp += (size_t)BATCH * SEQ * DM * 2;     // 4 MB
    f16* mem_f16 = (f16*)wp;  wp += (size_t)BATCH * MMEM * MEMD * 2;  // 0.25 MB
    f16* Wq_f16  = (f16*)wp;  wp += (size_t)DM * DM * 2;              // 2 MB
    f16* btbig   = (f16*)wp;  wp += (size_t)QLD * DM * 2;             // 3 MB
    f16* btcomb  = (f16*)wp;  wp += (size_t)KVLD * MEMD * 2;          // 2.5 MB
    f16* Wo_t    = (f16*)wp;  wp += (size_t)DM * DM * 2;              // 2 MB
    f16* W1q_t   = (f16*)wp;  wp += (size_t)RELH * DM * 2;            // 1 MB
    f16* qcat    = (f16*)wp;  wp += (size_t)BATCH * SEQ * QLD * 2;    // 6 MB
    f16* kvm     = (f16*)wp;  wp += (size_t)BATCH * MMEM * KVLD * 2;  // 1.25 MB
    f16* VoT     = (f16*)wp;  wp += (size_t)DM * BATCH * MMEM * 2;    // 0.5 MB
    f16* mpt     = (f16*)wp;  wp += (size_t)BATCH * MMEM * RELH * 2;  // 0.25 MB
    float* bcomb = (float*)wp; wp += (size_t)KVLD * 4;
    float* bqcomb= (float*)wp; wp += (size_t)QLD * 4;

    dim3 blk(256);

    // L1: casts + transposes + biases
    prep<<<dim3(2561), blk, 0, stream>>>(
        hs, mem, Wq, Wk, Wv, Wo, W1, bq, bk, bv, b1,
        hs_f16, mem_f16, Wq_f16, btbig, btcomb, Wo_t, W1q_t, bcomb, bqcomb);

    // L2: kvm GEMM + Wq1 weight-combine + bias-combine
    smallgemms<<<dim3(145), blk, 0, stream>>>(
        mem_f16, btcomb, bcomb, kvm,
        W1q_t, Wq_f16, btbig + (size_t)1024 * DM, bq, bqcomb);

    // L3: qcat GEMM + VoT GEMM + mpt
    biggemm<<<dim3(424), blk, 0, stream>>>(
        hs_f16, btbig, bqcomb, qcat, kvm, Wo_t, VoT, mpt);

    // L4: fused relevance + attention -> out, attn_w
    relattn<<<dim3(256), blk, 0, stream>>>(
        qcat, kvm, VoT, mpt, W2, b2, bo, out, attnw);
}